// Round 1
// baseline (2477.613 us; speedup 1.0000x reference)
//
#include <hip/hip_runtime.h>
#include <hip/hip_bf16.h>
#include <stdint.h>

// 2-layer LSTM, B=1024 T=80 E=100 U=512, bf16 MFMA path.
// R1: software-pipeline across timesteps — one launch runs layer2(t-1) || layer1(t)
// (independent): 81 dependent launches instead of 161, 4 blocks/CU. K-loop is
// double-buffered with global_load_lds (16B) async staging, one barrier/iter.
// R2: XCD-colocating tile swizzle — all 16 row-tiles of a unit-group g decode from
// block indices with lb%8 == g&7, so (assuming blockIdx%8 -> XCD round-robin) each
// XCD's L2 holds a launch-invariant ~0.83 MB weight slice + ~0.5 MB C slice across
// all 81 launches; only activations (~2.25 MB/XCD) stream from L3 each step.

#define B_ 1024
#define T_ 80

using bf16 = __hip_bfloat16;
typedef __attribute__((ext_vector_type(8))) short short8;
typedef __attribute__((ext_vector_type(4))) float f32x4;

__device__ __forceinline__ float sigf(float x) { return 1.f / (1.f + __expf(-x)); }
__device__ __forceinline__ float tanh_f(float x) { return 2.f / (1.f + __expf(-2.f * x)) - 1.f; }

typedef const __attribute__((address_space(1))) void* gp1_t;
typedef __attribute__((address_space(3))) void* lp3_t;
__device__ __forceinline__ void llds16(const void* g, void* l) {
  // per-lane global gather -> LDS wave-uniform base + lane*16
  __builtin_amdgcn_global_load_lds((gp1_t)g, (lp3_t)l, 16, 0, 0);
}

// XP[t][b][e] (e padded to 128 with zeros), bf16
__global__ void embed_kernel(const int* __restrict__ tokens, const float* __restrict__ emb,
                             bf16* __restrict__ XP) {
  int idx = blockIdx.x * 256 + threadIdx.x;  // over T_*B_*128
  int e = idx & 127;
  int bt = idx >> 7;
  int b = bt & (B_ - 1);
  int t = bt >> 10;
  if (t >= T_) return;
  int tok = tokens[b * T_ + t];
  float v = (e < 100) ? emb[tok * 100 + e] : 0.f;
  XP[idx] = __float2bfloat16(v);
}

// W [Kreal][2048] fp32 -> WT [2048][Kp] bf16, coalesced both ways via 32x32 LDS tile
__global__ void transpose_kernel(const float* __restrict__ W, bf16* __restrict__ WT,
                                 int Kreal, int Kp) {
  __shared__ float tile[32][33];
  int tn = blockIdx.x * 32;
  int tk = blockIdx.y * 32;
  int lx = threadIdx.x & 31;
  int ly = threadIdx.x >> 5;  // 8
#pragma unroll
  for (int r = ly; r < 32; r += 8) {
    int k = tk + r;
    tile[r][lx] = (k < Kreal) ? W[(size_t)k * 2048 + tn + lx] : 0.f;
  }
  __syncthreads();
#pragma unroll
  for (int r = ly; r < 32; r += 8) {
    WT[(size_t)(tn + r) * Kp + tk + lx] = __float2bfloat16(tile[lx][r]);
  }
}

struct CellParams {
  const bf16* A0; const bf16* B0;
  const bf16* A1; const bf16* B1;
  int lda0, ldb0, nkt0, lda1, ldb1, nkt1;
  const float* bias; float* C; bf16* H;
};

// z = A0@B0^T-seg + A1@B1^T-seg + bias; gates i,f,g,o; C fp32 in-place; H bf16 out.
// Block tile 64 rows x 16 units (64 z-cols). Dual-cell: blocks 0..511 -> p0,
// 512..1023 -> p1. LDS: 2 x (4KB A + 4KB B) staging, reused as 64x68 f32 z.
// Tile decode is XCD-colocating: lb bits [2:0]=g&7, [6:3]=bm, [8:7]=g>>3, so the
// 16 bm-tiles of unit-group g share lb%8 == g&7 -> same XCD under %8 round-robin.
// Bijective over lb in [0,512); only the bid->tile map changed vs R1 (perf-only).
__global__ __launch_bounds__(256) void cell_kernel(CellParams p0, CellParams p1) {
  __shared__ alignas(16) char smem[17408];
  const CellParams& p = (blockIdx.x >> 9) ? p1 : p0;
  const int lb = blockIdx.x & 511;
  const int g = (lb & 7) | ((lb >> 7) << 3);  // unit-group 0..31
  const int bm = (lb >> 3) & 15;              // 64-row tile
  const int u0 = g * 16;                      // unit offset
  const int tid = threadIdx.x;
  const int w = tid >> 6, l = tid & 63, q = l >> 4, m = l & 15;
  const int wm = w & 1, wn = w >> 1;

  // staging row pointers: wave w stages A rows w*16+m and B n-rows gate w, unit u0+m
  const bf16* arow0 = p.A0 + (size_t)(bm * 64 + w * 16 + m) * p.lda0;
  const bf16* brow0 = p.B0 + (size_t)(w * 512 + u0 + m) * p.ldb0;
  const bf16* arow1 = p.A1 + (size_t)(bm * 64 + w * 16 + m) * p.lda1;
  const bf16* brow1 = p.B1 + (size_t)(w * 512 + u0 + m) * p.ldb1;
  const int woff = w * 1024;  // lane l lands at woff + l*16 (== q*256 + m*16)

  auto stage = [&](int kt, int buf) {
    const bf16 *ga, *gb;
    if (kt < p.nkt0) { int k0 = kt * 32 + q * 8; ga = arow0 + k0; gb = brow0 + k0; }
    else { int k0 = (kt - p.nkt0) * 32 + q * 8; ga = arow1 + k0; gb = brow1 + k0; }
    char* base = smem + buf * 8192 + woff;
    llds16(ga, base);          // A: [16-row group w][chunk q][m][16B]
    llds16(gb, base + 4096);   // B: same layout, n-rows
  };

  f32x4 acc00 = {0.f, 0.f, 0.f, 0.f};
  f32x4 acc01 = {0.f, 0.f, 0.f, 0.f};
  f32x4 acc10 = {0.f, 0.f, 0.f, 0.f};
  f32x4 acc11 = {0.f, 0.f, 0.f, 0.f};

  const int fA0 = wm * 2048 + q * 256 + m * 16;
  const int fA1 = fA0 + 1024;
  const int fB0 = 4096 + wn * 2048 + q * 256 + m * 16;
  const int fB1 = fB0 + 1024;

  const int total = p.nkt0 + p.nkt1;
  stage(0, 0);
  for (int kt = 0; kt < total; ++kt) {
    const int cb = (kt & 1) * 8192;
    __syncthreads();                         // drains this wave's loads (vmcnt0) + barrier
    if (kt + 1 < total) stage(kt + 1, (kt + 1) & 1);  // async prefetch, lands by next barrier
    short8 a0 = *(const short8*)(smem + cb + fA0);
    short8 a1 = *(const short8*)(smem + cb + fA1);
    short8 b0 = *(const short8*)(smem + cb + fB0);
    short8 b1 = *(const short8*)(smem + cb + fB1);
    acc00 = __builtin_amdgcn_mfma_f32_16x16x32_bf16(a0, b0, acc00, 0, 0, 0);
    acc01 = __builtin_amdgcn_mfma_f32_16x16x32_bf16(a0, b1, acc01, 0, 0, 0);
    acc10 = __builtin_amdgcn_mfma_f32_16x16x32_bf16(a1, b0, acc10, 0, 0, 0);
    acc11 = __builtin_amdgcn_mfma_f32_16x16x32_bf16(a1, b1, acc11, 0, 0, 0);
  }

  __syncthreads();
  float* zs = (float*)smem;  // [64][68]
#pragma unroll
  for (int r = 0; r < 4; ++r) {
    int rr = q * 4 + r;
    zs[(wm * 32 + rr) * 68 + wn * 32 + m] = acc00[r];
    zs[(wm * 32 + rr) * 68 + wn * 32 + 16 + m] = acc01[r];
    zs[(wm * 32 + 16 + rr) * 68 + wn * 32 + m] = acc10[r];
    zs[(wm * 32 + 16 + rr) * 68 + wn * 32 + 16 + m] = acc11[r];
  }
  __syncthreads();

  const int uu = tid & 15;
  const int r0 = tid >> 4;
  const int gu = u0 + uu;
  const float bi = p.bias[0 * 512 + gu];
  const float bf = p.bias[1 * 512 + gu];
  const float bg = p.bias[2 * 512 + gu];
  const float bo = p.bias[3 * 512 + gu];
#pragma unroll
  for (int pp = 0; pp < 4; ++pp) {
    int row = r0 + pp * 16;
    float zi = zs[row * 68 + 0 + uu] + bi;
    float zf = zs[row * 68 + 16 + uu] + bf;
    float zg = zs[row * 68 + 32 + uu] + bg;
    float zo = zs[row * 68 + 48 + uu] + bo;
    size_t gi = (size_t)(bm * 64 + row) * 512 + gu;
    float c = sigf(zf) * p.C[gi] + sigf(zi) * tanh_f(zg);
    float h = sigf(zo) * tanh_f(c);
    p.C[gi] = c;
    p.H[gi] = __float2bfloat16(h);
  }
}

// out[b] = sigmoid(h2[b,:] @ Wout + bout); one wave per row
__global__ void output_kernel(const bf16* __restrict__ H2, const float* __restrict__ Wout,
                              const float* __restrict__ bout, float* __restrict__ out) {
  int w = threadIdx.x >> 6, l = threadIdx.x & 63;
  int row = blockIdx.x * 4 + w;
  const bf16* h = H2 + (size_t)row * 512;
  float s = 0.f;
#pragma unroll
  for (int k = 0; k < 8; ++k) {
    int kk = l + k * 64;
    s += __bfloat162float(h[kk]) * Wout[kk];
  }
#pragma unroll
  for (int off = 32; off > 0; off >>= 1) s += __shfl_down(s, off);
  if (l == 0) out[row] = sigf(s + bout[0]);
}

extern "C" void kernel_launch(void* const* d_in, const int* in_sizes, int n_in,
                              void* d_out, int out_size, void* d_ws, size_t ws_size,
                              hipStream_t stream) {
  const int* tokens = (const int*)d_in[0];
  const float* emb = (const float*)d_in[1];
  const float* W1 = (const float*)d_in[2];
  const float* U1 = (const float*)d_in[3];
  const float* b1 = (const float*)d_in[4];
  const float* W2 = (const float*)d_in[5];
  const float* U2 = (const float*)d_in[6];
  const float* b2 = (const float*)d_in[7];
  const float* Wout = (const float*)d_in[8];
  const float* bout = (const float*)d_in[9];
  float* out = (float*)d_out;
  char* ws = (char*)d_ws;

  const size_t oXP = 0;          // 80*1024*128 bf16 = 20971520
  const size_t oW1T = 20971520;  // 2048*128 bf16
  const size_t oU1T = 21495808;  // 2048*512 bf16
  const size_t oW2T = 23592960;
  const size_t oU2T = 25690112;
  const size_t oH1 = 27787264;   // 2 x 1024*512 bf16
  const size_t oH2 = 29884416;
  const size_t oC1 = 31981568;   // 1024*512 f32
  const size_t oC2 = 34078720;
  if (ws_size < 36175872) return;

  bf16* XP = (bf16*)(ws + oXP);
  bf16* W1T = (bf16*)(ws + oW1T);
  bf16* U1T = (bf16*)(ws + oU1T);
  bf16* W2T = (bf16*)(ws + oW2T);
  bf16* U2T = (bf16*)(ws + oU2T);
  bf16* H1 = (bf16*)(ws + oH1);
  bf16* H2 = (bf16*)(ws + oH2);
  float* C1 = (float*)(ws + oC1);
  float* C2 = (float*)(ws + oC2);

  hipMemsetAsync(ws + oH1, 0, 1048576, stream);  // H1 buf0
  hipMemsetAsync(ws + oH2, 0, 1048576, stream);  // H2 buf0
  hipMemsetAsync(ws + oC1, 0, 4194304, stream);  // C1 + C2

  embed_kernel<<<40960, 256, 0, stream>>>(tokens, emb, XP);
  transpose_kernel<<<dim3(64, 4), 256, 0, stream>>>(W1, W1T, 100, 128);
  transpose_kernel<<<dim3(64, 16), 256, 0, stream>>>(U1, U1T, 512, 512);
  transpose_kernel<<<dim3(64, 16), 256, 0, stream>>>(W2, W2T, 512, 512);
  transpose_kernel<<<dim3(64, 16), 256, 0, stream>>>(U2, U2T, 512, 512);

  auto mkL1 = [&](int t) {
    CellParams p;
    p.A0 = XP + (size_t)t * 131072; p.B0 = W1T; p.lda0 = 128; p.ldb0 = 128; p.nkt0 = 4;
    p.A1 = H1 + (size_t)(t & 1) * 524288; p.B1 = U1T; p.lda1 = 512; p.ldb1 = 512; p.nkt1 = 16;
    p.bias = b1; p.C = C1; p.H = H1 + (size_t)((t + 1) & 1) * 524288;
    return p;
  };
  auto mkL2 = [&](int t) {
    CellParams p;
    p.A0 = H1 + (size_t)((t + 1) & 1) * 524288; p.B0 = W2T; p.lda0 = 512; p.ldb0 = 512; p.nkt0 = 16;
    p.A1 = H2 + (size_t)(t & 1) * 524288; p.B1 = U2T; p.lda1 = 512; p.ldb1 = 512; p.nkt1 = 16;
    p.bias = b2; p.C = C2; p.H = H2 + (size_t)((t + 1) & 1) * 524288;
    return p;
  };

  cell_kernel<<<512, 256, 0, stream>>>(mkL1(0), mkL1(0));
  for (int k = 1; k < T_; ++k)
    cell_kernel<<<1024, 256, 0, stream>>>(mkL2(k - 1), mkL1(k));  // layer2(k-1) || layer1(k)
  cell_kernel<<<512, 256, 0, stream>>>(mkL2(T_ - 1), mkL2(T_ - 1));

  // final h2 in buffer (T_&1)==0
  output_kernel<<<256, 256, 0, stream>>>(H2, Wout, bout, out);
}

// Round 2
// 2427.910 us; speedup vs baseline: 1.0205x; 1.0205x over previous
//
#include <hip/hip_runtime.h>
#include <hip/hip_bf16.h>
#include <stdint.h>

// 2-layer LSTM, B=1024 T=80 E=100 U=512, bf16 MFMA path.
// R1: software-pipeline across timesteps — one launch runs layer2(t-1) || layer1(t).
// R2: XCD-colocating tile swizzle (neutral, kept).
// R3: K-loop pipeline depth 1 -> 3 (T3/T4): 4 LDS staging buffers, raw s_barrier +
// counted s_waitcnt vmcnt(4) instead of __syncthreads' vmcnt(0) drain. Each stage's
// loads now get ~3 iterations to land instead of ~1, hiding L2/L3 latency.

#define B_ 1024
#define T_ 80

using bf16 = __hip_bfloat16;
typedef __attribute__((ext_vector_type(8))) short short8;
typedef __attribute__((ext_vector_type(4))) float f32x4;

__device__ __forceinline__ float sigf(float x) { return 1.f / (1.f + __expf(-x)); }
__device__ __forceinline__ float tanh_f(float x) { return 2.f / (1.f + __expf(-2.f * x)) - 1.f; }

typedef const __attribute__((address_space(1))) void* gp1_t;
typedef __attribute__((address_space(3))) void* lp3_t;
__device__ __forceinline__ void llds16(const void* g, void* l) {
  // per-lane global gather -> LDS wave-uniform base + lane*16
  __builtin_amdgcn_global_load_lds((gp1_t)g, (lp3_t)l, 16, 0, 0);
}

// XP[t][b][e] (e padded to 128 with zeros), bf16
__global__ void embed_kernel(const int* __restrict__ tokens, const float* __restrict__ emb,
                             bf16* __restrict__ XP) {
  int idx = blockIdx.x * 256 + threadIdx.x;  // over T_*B_*128
  int e = idx & 127;
  int bt = idx >> 7;
  int b = bt & (B_ - 1);
  int t = bt >> 10;
  if (t >= T_) return;
  int tok = tokens[b * T_ + t];
  float v = (e < 100) ? emb[tok * 100 + e] : 0.f;
  XP[idx] = __float2bfloat16(v);
}

// W [Kreal][2048] fp32 -> WT [2048][Kp] bf16, coalesced both ways via 32x32 LDS tile
__global__ void transpose_kernel(const float* __restrict__ W, bf16* __restrict__ WT,
                                 int Kreal, int Kp) {
  __shared__ float tile[32][33];
  int tn = blockIdx.x * 32;
  int tk = blockIdx.y * 32;
  int lx = threadIdx.x & 31;
  int ly = threadIdx.x >> 5;  // 8
#pragma unroll
  for (int r = ly; r < 32; r += 8) {
    int k = tk + r;
    tile[r][lx] = (k < Kreal) ? W[(size_t)k * 2048 + tn + lx] : 0.f;
  }
  __syncthreads();
#pragma unroll
  for (int r = ly; r < 32; r += 8) {
    WT[(size_t)(tn + r) * Kp + tk + lx] = __float2bfloat16(tile[lx][r]);
  }
}

struct CellParams {
  const bf16* A0; const bf16* B0;
  const bf16* A1; const bf16* B1;
  int lda0, ldb0, nkt0, lda1, ldb1, nkt1;
  const float* bias; float* C; bf16* H;
};

// z = A0@B0^T-seg + A1@B1^T-seg + bias; gates i,f,g,o; C fp32 in-place; H bf16 out.
// Block tile 64 rows x 16 units (64 z-cols). Dual-cell: blocks 0..511 -> p0,
// 512..1023 -> p1. LDS: 4 x (4KB A + 4KB B) staging ring, reused as 64x68 f32 z.
// K-loop: depth-3 prefetch. Per iter: wait own vmcnt(4) (2 loads per stage, 2 future
// stages in flight) -> s_barrier (=> ALL waves' stage-k loads landed) -> issue
// stage(k+3) -> ds_read + MFMA (compiler inserts lgkm waits). stage(k+3) overwrites
// buf[(k-1)&3], whose readers lgkm-drained before barrier k -> safe. Tail peels to
// vmcnt(2)/vmcnt(0) as the in-flight count shrinks.
__global__ __launch_bounds__(256) void cell_kernel(CellParams p0, CellParams p1) {
  __shared__ alignas(16) char smem[32768];
  const CellParams& p = (blockIdx.x >> 9) ? p1 : p0;
  const int lb = blockIdx.x & 511;
  const int g = (lb & 7) | ((lb >> 7) << 3);  // unit-group 0..31
  const int bm = (lb >> 3) & 15;              // 64-row tile
  const int u0 = g * 16;                      // unit offset
  const int tid = threadIdx.x;
  const int w = tid >> 6, l = tid & 63, q = l >> 4, m = l & 15;
  const int wm = w & 1, wn = w >> 1;

  // staging row pointers: wave w stages A rows w*16+m and B n-rows gate w, unit u0+m
  const bf16* arow0 = p.A0 + (size_t)(bm * 64 + w * 16 + m) * p.lda0;
  const bf16* brow0 = p.B0 + (size_t)(w * 512 + u0 + m) * p.ldb0;
  const bf16* arow1 = p.A1 + (size_t)(bm * 64 + w * 16 + m) * p.lda1;
  const bf16* brow1 = p.B1 + (size_t)(w * 512 + u0 + m) * p.ldb1;
  const int woff = w * 1024;  // lane l lands at woff + l*16 (== q*256 + m*16)

  auto stage = [&](int kt, int buf) {
    const bf16 *ga, *gb;
    if (kt < p.nkt0) { int k0 = kt * 32 + q * 8; ga = arow0 + k0; gb = brow0 + k0; }
    else { int k0 = (kt - p.nkt0) * 32 + q * 8; ga = arow1 + k0; gb = brow1 + k0; }
    char* base = smem + buf * 8192 + woff;
    llds16(ga, base);          // A: [16-row group w][chunk q][m][16B]
    llds16(gb, base + 4096);   // B: same layout, n-rows
  };

  f32x4 acc00 = {0.f, 0.f, 0.f, 0.f};
  f32x4 acc01 = {0.f, 0.f, 0.f, 0.f};
  f32x4 acc10 = {0.f, 0.f, 0.f, 0.f};
  f32x4 acc11 = {0.f, 0.f, 0.f, 0.f};

  const int fA0 = wm * 2048 + q * 256 + m * 16;
  const int fA1 = fA0 + 1024;
  const int fB0 = 4096 + wn * 2048 + q * 256 + m * 16;
  const int fB1 = fB0 + 1024;

  const int total = p.nkt0 + p.nkt1;  // 20 (layer1) or 32 (layer2), both >= 4
  stage(0, 0);
  stage(1, 1);
  stage(2, 2);
  for (int kt = 0; kt < total; ++kt) {
    const int rem = total - 1 - kt;
    // own loads for stage kt (and older) have landed after this wait:
    if (rem >= 2)      asm volatile("s_waitcnt vmcnt(4)" ::: "memory");
    else if (rem == 1) asm volatile("s_waitcnt vmcnt(2)" ::: "memory");
    else               asm volatile("s_waitcnt vmcnt(0)" ::: "memory");
    __builtin_amdgcn_s_barrier();  // now everyone's stage-kt loads have landed
    if (kt + 3 < total) stage(kt + 3, (kt + 3) & 3);  // overwrites buf[(kt-1)&3]
    const int cb = (kt & 3) * 8192;
    short8 a0 = *(const short8*)(smem + cb + fA0);
    short8 a1 = *(const short8*)(smem + cb + fA1);
    short8 b0 = *(const short8*)(smem + cb + fB0);
    short8 b1 = *(const short8*)(smem + cb + fB1);
    acc00 = __builtin_amdgcn_mfma_f32_16x16x32_bf16(a0, b0, acc00, 0, 0, 0);
    acc01 = __builtin_amdgcn_mfma_f32_16x16x32_bf16(a0, b1, acc01, 0, 0, 0);
    acc10 = __builtin_amdgcn_mfma_f32_16x16x32_bf16(a1, b0, acc10, 0, 0, 0);
    acc11 = __builtin_amdgcn_mfma_f32_16x16x32_bf16(a1, b1, acc11, 0, 0, 0);
  }

  __syncthreads();
  float* zs = (float*)smem;  // [64][68]
#pragma unroll
  for (int r = 0; r < 4; ++r) {
    int rr = q * 4 + r;
    zs[(wm * 32 + rr) * 68 + wn * 32 + m] = acc00[r];
    zs[(wm * 32 + rr) * 68 + wn * 32 + 16 + m] = acc01[r];
    zs[(wm * 32 + 16 + rr) * 68 + wn * 32 + m] = acc10[r];
    zs[(wm * 32 + 16 + rr) * 68 + wn * 32 + 16 + m] = acc11[r];
  }
  __syncthreads();

  const int uu = tid & 15;
  const int r0 = tid >> 4;
  const int gu = u0 + uu;
  const float bi = p.bias[0 * 512 + gu];
  const float bf = p.bias[1 * 512 + gu];
  const float bg = p.bias[2 * 512 + gu];
  const float bo = p.bias[3 * 512 + gu];
#pragma unroll
  for (int pp = 0; pp < 4; ++pp) {
    int row = r0 + pp * 16;
    float zi = zs[row * 68 + 0 + uu] + bi;
    float zf = zs[row * 68 + 16 + uu] + bf;
    float zg = zs[row * 68 + 32 + uu] + bg;
    float zo = zs[row * 68 + 48 + uu] + bo;
    size_t gi = (size_t)(bm * 64 + row) * 512 + gu;
    float c = sigf(zf) * p.C[gi] + sigf(zi) * tanh_f(zg);
    float h = sigf(zo) * tanh_f(c);
    p.C[gi] = c;
    p.H[gi] = __float2bfloat16(h);
  }
}

// out[b] = sigmoid(h2[b,:] @ Wout + bout); one wave per row
__global__ void output_kernel(const bf16* __restrict__ H2, const float* __restrict__ Wout,
                              const float* __restrict__ bout, float* __restrict__ out) {
  int w = threadIdx.x >> 6, l = threadIdx.x & 63;
  int row = blockIdx.x * 4 + w;
  const bf16* h = H2 + (size_t)row * 512;
  float s = 0.f;
#pragma unroll
  for (int k = 0; k < 8; ++k) {
    int kk = l + k * 64;
    s += __bfloat162float(h[kk]) * Wout[kk];
  }
#pragma unroll
  for (int off = 32; off > 0; off >>= 1) s += __shfl_down(s, off);
  if (l == 0) out[row] = sigf(s + bout[0]);
}

extern "C" void kernel_launch(void* const* d_in, const int* in_sizes, int n_in,
                              void* d_out, int out_size, void* d_ws, size_t ws_size,
                              hipStream_t stream) {
  const int* tokens = (const int*)d_in[0];
  const float* emb = (const float*)d_in[1];
  const float* W1 = (const float*)d_in[2];
  const float* U1 = (const float*)d_in[3];
  const float* b1 = (const float*)d_in[4];
  const float* W2 = (const float*)d_in[5];
  const float* U2 = (const float*)d_in[6];
  const float* b2 = (const float*)d_in[7];
  const float* Wout = (const float*)d_in[8];
  const float* bout = (const float*)d_in[9];
  float* out = (float*)d_out;
  char* ws = (char*)d_ws;

  const size_t oXP = 0;          // 80*1024*128 bf16 = 20971520
  const size_t oW1T = 20971520;  // 2048*128 bf16
  const size_t oU1T = 21495808;  // 2048*512 bf16
  const size_t oW2T = 23592960;
  const size_t oU2T = 25690112;
  const size_t oH1 = 27787264;   // 2 x 1024*512 bf16
  const size_t oH2 = 29884416;
  const size_t oC1 = 31981568;   // 1024*512 f32
  const size_t oC2 = 34078720;
  if (ws_size < 36175872) return;

  bf16* XP = (bf16*)(ws + oXP);
  bf16* W1T = (bf16*)(ws + oW1T);
  bf16* U1T = (bf16*)(ws + oU1T);
  bf16* W2T = (bf16*)(ws + oW2T);
  bf16* U2T = (bf16*)(ws + oU2T);
  bf16* H1 = (bf16*)(ws + oH1);
  bf16* H2 = (bf16*)(ws + oH2);
  float* C1 = (float*)(ws + oC1);
  float* C2 = (float*)(ws + oC2);

  hipMemsetAsync(ws + oH1, 0, 1048576, stream);  // H1 buf0
  hipMemsetAsync(ws + oH2, 0, 1048576, stream);  // H2 buf0
  hipMemsetAsync(ws + oC1, 0, 4194304, stream);  // C1 + C2

  embed_kernel<<<40960, 256, 0, stream>>>(tokens, emb, XP);
  transpose_kernel<<<dim3(64, 4), 256, 0, stream>>>(W1, W1T, 100, 128);
  transpose_kernel<<<dim3(64, 16), 256, 0, stream>>>(U1, U1T, 512, 512);
  transpose_kernel<<<dim3(64, 16), 256, 0, stream>>>(W2, W2T, 512, 512);
  transpose_kernel<<<dim3(64, 16), 256, 0, stream>>>(U2, U2T, 512, 512);

  auto mkL1 = [&](int t) {
    CellParams p;
    p.A0 = XP + (size_t)t * 131072; p.B0 = W1T; p.lda0 = 128; p.ldb0 = 128; p.nkt0 = 4;
    p.A1 = H1 + (size_t)(t & 1) * 524288; p.B1 = U1T; p.lda1 = 512; p.ldb1 = 512; p.nkt1 = 16;
    p.bias = b1; p.C = C1; p.H = H1 + (size_t)((t + 1) & 1) * 524288;
    return p;
  };
  auto mkL2 = [&](int t) {
    CellParams p;
    p.A0 = H1 + (size_t)((t + 1) & 1) * 524288; p.B0 = W2T; p.lda0 = 512; p.ldb0 = 512; p.nkt0 = 16;
    p.A1 = H2 + (size_t)(t & 1) * 524288; p.B1 = U2T; p.lda1 = 512; p.ldb1 = 512; p.nkt1 = 16;
    p.bias = b2; p.C = C2; p.H = H2 + (size_t)((t + 1) & 1) * 524288;
    return p;
  };

  cell_kernel<<<512, 256, 0, stream>>>(mkL1(0), mkL1(0));
  for (int k = 1; k < T_; ++k)
    cell_kernel<<<1024, 256, 0, stream>>>(mkL2(k - 1), mkL1(k));  // layer2(k-1) || layer1(k)
  cell_kernel<<<512, 256, 0, stream>>>(mkL2(T_ - 1), mkL2(T_ - 1));

  // final h2 in buffer (T_&1)==0
  output_kernel<<<256, 256, 0, stream>>>(H2, Wout, bout, out);
}

// Round 3
// 1777.627 us; speedup vs baseline: 1.3938x; 1.3658x over previous
//
#include <hip/hip_runtime.h>
#include <hip/hip_bf16.h>
#include <stdint.h>

// 2-layer LSTM, B=1024 T=80 E=100 U=512, bf16 MFMA path.
// R1: software-pipeline across timesteps — one launch runs layer2(t-1) || layer1(t).
// R2: XCD-colocating tile swizzle (neutral, kept).
// R3: K-loop depth-3 prefetch, 4-buffer LDS ring, counted s_waitcnt vmcnt (neutral ->
//     K-loop is not latency-bound; kept for the new low-occupancy regime).
// R4: 128x128 output tile (was 64x64): halves chip-level staged bytes per launch
//     (218 MB -> 109 MB) on the theory that we are cache-fabric-BW-bound at ~7.5 TB/s.
//     256 blocks/launch = 1 block/CU, 512 threads = 8 waves; wave computes 64x32
//     (8 MFMA per k-step from 4 A-frags x 2 B-frags). Epilogue via 64x133 LDS z-tile
//     in two passes, float4 C and ushort4 H vectorized.

#define B_ 1024
#define T_ 80

using bf16 = __hip_bfloat16;
typedef __attribute__((ext_vector_type(8))) short short8;
typedef __attribute__((ext_vector_type(4))) float f32x4;
typedef __attribute__((ext_vector_type(4))) unsigned short ushort4v;

__device__ __forceinline__ float sigf(float x) { return 1.f / (1.f + __expf(-x)); }
__device__ __forceinline__ float tanh_f(float x) { return 2.f / (1.f + __expf(-2.f * x)) - 1.f; }

typedef const __attribute__((address_space(1))) void* gp1_t;
typedef __attribute__((address_space(3))) void* lp3_t;
__device__ __forceinline__ void llds16(const void* g, void* l) {
  // per-lane global gather -> LDS wave-uniform base + lane*16
  __builtin_amdgcn_global_load_lds((gp1_t)g, (lp3_t)l, 16, 0, 0);
}

// XP[t][b][e] (e padded to 128 with zeros), bf16
__global__ void embed_kernel(const int* __restrict__ tokens, const float* __restrict__ emb,
                             bf16* __restrict__ XP) {
  int idx = blockIdx.x * 256 + threadIdx.x;  // over T_*B_*128
  int e = idx & 127;
  int bt = idx >> 7;
  int b = bt & (B_ - 1);
  int t = bt >> 10;
  if (t >= T_) return;
  int tok = tokens[b * T_ + t];
  float v = (e < 100) ? emb[tok * 100 + e] : 0.f;
  XP[idx] = __float2bfloat16(v);
}

// W [Kreal][2048] fp32 -> WT [2048][Kp] bf16, coalesced both ways via 32x32 LDS tile
__global__ void transpose_kernel(const float* __restrict__ W, bf16* __restrict__ WT,
                                 int Kreal, int Kp) {
  __shared__ float tile[32][33];
  int tn = blockIdx.x * 32;
  int tk = blockIdx.y * 32;
  int lx = threadIdx.x & 31;
  int ly = threadIdx.x >> 5;  // 8
#pragma unroll
  for (int r = ly; r < 32; r += 8) {
    int k = tk + r;
    tile[r][lx] = (k < Kreal) ? W[(size_t)k * 2048 + tn + lx] : 0.f;
  }
  __syncthreads();
#pragma unroll
  for (int r = ly; r < 32; r += 8) {
    WT[(size_t)(tn + r) * Kp + tk + lx] = __float2bfloat16(tile[lx][r]);
  }
}

struct CellParams {
  const bf16* A0; const bf16* B0;
  const bf16* A1; const bf16* B1;
  int lda0, ldb0, nkt0, lda1, ldb1, nkt1;
  const float* bias; float* C; bf16* H;
};

// z = A0@B0^T-seg + A1@B1^T-seg + bias; gates i,f,g,o; C fp32 in-place; H bf16 out.
// Block tile 128 rows x 32 units (128 z-cols = 4 gates x 32 units). Dual-cell:
// blocks 0..127 -> p0, 128..255 -> p1. 512 threads = 8 waves as 2(m) x 4(n);
// wave tile 64 rows x 32 cols = 4x2 16x16 frags.
// LDS: 4 x (8KB A + 8KB B) staging ring (64 KB); epilogue reuses it as 64x133 f32 z.
// K-loop: depth-3 prefetch, per-wave 2 loads/stage -> steady-state wait vmcnt(4),
// then s_barrier (=> ALL waves' stage-kt loads landed), issue stage(kt+3)
// (overwrites buf[(kt-1)&3], drained last iter). Tail peels vmcnt(2)/vmcnt(0).
__global__ __launch_bounds__(512) void cell_kernel(CellParams p0, CellParams p1) {
  __shared__ alignas(16) char smem[65536];
  const CellParams& p = (blockIdx.x >> 7) ? p1 : p0;
  const int lb = blockIdx.x & 127;
  const int g = (lb & 7) | ((lb >> 6) << 3);  // unit-group 0..15 (XCD-colocated: lb%8)
  const int bm = (lb >> 3) & 7;               // 128-row tile 0..7
  const int u0 = g * 32;                      // unit offset
  const int tid = threadIdx.x;
  const int w = tid >> 6, l = tid & 63, q = l >> 4, m = l & 15;
  const int wm = w >> 2, wn = w & 3;

  // staging: wave w stages A rows bm*128 + w*16 + m, and B n-rows for gate w>>1,
  // units u0 + (w&1)*16 + m. Lane l lands at LDS base + l*16 (HW rule).
  const bf16* arow0 = p.A0 + (size_t)(bm * 128 + w * 16 + m) * p.lda0;
  const bf16* brow0 = p.B0 + (size_t)((w >> 1) * 512 + u0 + (w & 1) * 16 + m) * p.ldb0;
  const bf16* arow1 = p.A1 + (size_t)(bm * 128 + w * 16 + m) * p.lda1;
  const bf16* brow1 = p.B1 + (size_t)((w >> 1) * 512 + u0 + (w & 1) * 16 + m) * p.ldb1;

  auto stage = [&](int kt, int buf) {
    const bf16 *ga, *gb;
    if (kt < p.nkt0) { int k0 = kt * 32 + q * 8; ga = arow0 + k0; gb = brow0 + k0; }
    else { int k0 = (kt - p.nkt0) * 32 + q * 8; ga = arow1 + k0; gb = brow1 + k0; }
    char* base = smem + buf * 16384 + w * 1024;
    llds16(ga, base);          // A: [wave-group w][chunk q][m][16B]
    llds16(gb, base + 8192);   // B: same layout, n-rows
  };

  f32x4 acc[4][2];
#pragma unroll
  for (int mi = 0; mi < 4; ++mi)
#pragma unroll
    for (int nj = 0; nj < 2; ++nj) acc[mi][nj] = (f32x4){0.f, 0.f, 0.f, 0.f};

  const int fbase = q * 256 + m * 16;
  const int total = p.nkt0 + p.nkt1;  // 20 (layer1) or 32 (layer2)
  stage(0, 0);
  stage(1, 1);
  stage(2, 2);
  for (int kt = 0; kt < total; ++kt) {
    const int rem = total - 1 - kt;
    if (rem >= 2)      asm volatile("s_waitcnt vmcnt(4)" ::: "memory");
    else if (rem == 1) asm volatile("s_waitcnt vmcnt(2)" ::: "memory");
    else               asm volatile("s_waitcnt vmcnt(0)" ::: "memory");
    __builtin_amdgcn_s_barrier();  // everyone's stage-kt loads have landed
    if (kt + 3 < total) stage(kt + 3, (kt + 3) & 3);
    const int cb = (kt & 3) * 16384;
    short8 a[4], b[2];
#pragma unroll
    for (int mi = 0; mi < 4; ++mi)
      a[mi] = *(const short8*)(smem + cb + (wm * 4 + mi) * 1024 + fbase);
#pragma unroll
    for (int nj = 0; nj < 2; ++nj)
      b[nj] = *(const short8*)(smem + cb + 8192 + (wn * 2 + nj) * 1024 + fbase);
#pragma unroll
    for (int mi = 0; mi < 4; ++mi)
#pragma unroll
      for (int nj = 0; nj < 2; ++nj)
        acc[mi][nj] = __builtin_amdgcn_mfma_f32_16x16x32_bf16(a[mi], b[nj], acc[mi][nj], 0, 0, 0);
  }

  __syncthreads();
  float* zs = (float*)smem;  // [64][133] f32 = 34 KB (does not overlap buf3=last-read)
  const int erow = tid >> 3;        // 0..63
  const int ub = (tid & 7) * 4;     // unit base within group, 0..28
  float bi[4], bff[4], bg[4], bo[4];
#pragma unroll
  for (int j = 0; j < 4; ++j) {
    int gu = u0 + ub + j;
    bi[j] = p.bias[gu];
    bff[j] = p.bias[512 + gu];
    bg[j] = p.bias[1024 + gu];
    bo[j] = p.bias[1536 + gu];
  }
#pragma unroll
  for (int pass = 0; pass < 2; ++pass) {
    if (pass) __syncthreads();  // protect zs from overwrite while pass-0 reads finish
    if (wm == pass) {
#pragma unroll
      for (int mi = 0; mi < 4; ++mi)
#pragma unroll
        for (int nj = 0; nj < 2; ++nj)
#pragma unroll
          for (int r = 0; r < 4; ++r)
            zs[(mi * 16 + q * 4 + r) * 133 + wn * 32 + nj * 16 + m] = acc[mi][nj][r];
    }
    __syncthreads();
    int grow = bm * 128 + pass * 64 + erow;
    size_t gi = (size_t)grow * 512 + u0 + ub;
    float4 cold = *(const float4*)(p.C + gi);
    float cn[4];
    unsigned short hv[4];
#pragma unroll
    for (int j = 0; j < 4; ++j) {
      float zi = zs[erow * 133 + ub + j] + bi[j];
      float zf = zs[erow * 133 + 32 + ub + j] + bff[j];
      float zg = zs[erow * 133 + 64 + ub + j] + bg[j];
      float zo = zs[erow * 133 + 96 + ub + j] + bo[j];
      float co = (j == 0) ? cold.x : (j == 1) ? cold.y : (j == 2) ? cold.z : cold.w;
      float c = sigf(zf) * co + sigf(zi) * tanh_f(zg);
      float h = sigf(zo) * tanh_f(c);
      cn[j] = c;
      bf16 hb = __float2bfloat16(h);
      hv[j] = *(unsigned short*)&hb;
    }
    *(float4*)(p.C + gi) = make_float4(cn[0], cn[1], cn[2], cn[3]);
    *(ushort4v*)(p.H + gi) = (ushort4v){hv[0], hv[1], hv[2], hv[3]};
  }
}

// out[b] = sigmoid(h2[b,:] @ Wout + bout); one wave per row
__global__ void output_kernel(const bf16* __restrict__ H2, const float* __restrict__ Wout,
                              const float* __restrict__ bout, float* __restrict__ out) {
  int w = threadIdx.x >> 6, l = threadIdx.x & 63;
  int row = blockIdx.x * 4 + w;
  const bf16* h = H2 + (size_t)row * 512;
  float s = 0.f;
#pragma unroll
  for (int k = 0; k < 8; ++k) {
    int kk = l + k * 64;
    s += __bfloat162float(h[kk]) * Wout[kk];
  }
#pragma unroll
  for (int off = 32; off > 0; off >>= 1) s += __shfl_down(s, off);
  if (l == 0) out[row] = sigf(s + bout[0]);
}

extern "C" void kernel_launch(void* const* d_in, const int* in_sizes, int n_in,
                              void* d_out, int out_size, void* d_ws, size_t ws_size,
                              hipStream_t stream) {
  const int* tokens = (const int*)d_in[0];
  const float* emb = (const float*)d_in[1];
  const float* W1 = (const float*)d_in[2];
  const float* U1 = (const float*)d_in[3];
  const float* b1 = (const float*)d_in[4];
  const float* W2 = (const float*)d_in[5];
  const float* U2 = (const float*)d_in[6];
  const float* b2 = (const float*)d_in[7];
  const float* Wout = (const float*)d_in[8];
  const float* bout = (const float*)d_in[9];
  float* out = (float*)d_out;
  char* ws = (char*)d_ws;

  const size_t oXP = 0;          // 80*1024*128 bf16 = 20971520
  const size_t oW1T = 20971520;  // 2048*128 bf16
  const size_t oU1T = 21495808;  // 2048*512 bf16
  const size_t oW2T = 23592960;
  const size_t oU2T = 25690112;
  const size_t oH1 = 27787264;   // 2 x 1024*512 bf16
  const size_t oH2 = 29884416;
  const size_t oC1 = 31981568;   // 1024*512 f32
  const size_t oC2 = 34078720;
  if (ws_size < 36175872) return;

  bf16* XP = (bf16*)(ws + oXP);
  bf16* W1T = (bf16*)(ws + oW1T);
  bf16* U1T = (bf16*)(ws + oU1T);
  bf16* W2T = (bf16*)(ws + oW2T);
  bf16* U2T = (bf16*)(ws + oU2T);
  bf16* H1 = (bf16*)(ws + oH1);
  bf16* H2 = (bf16*)(ws + oH2);
  float* C1 = (float*)(ws + oC1);
  float* C2 = (float*)(ws + oC2);

  hipMemsetAsync(ws + oH1, 0, 1048576, stream);  // H1 buf0
  hipMemsetAsync(ws + oH2, 0, 1048576, stream);  // H2 buf0
  hipMemsetAsync(ws + oC1, 0, 4194304, stream);  // C1 + C2

  embed_kernel<<<40960, 256, 0, stream>>>(tokens, emb, XP);
  transpose_kernel<<<dim3(64, 4), 256, 0, stream>>>(W1, W1T, 100, 128);
  transpose_kernel<<<dim3(64, 16), 256, 0, stream>>>(U1, U1T, 512, 512);
  transpose_kernel<<<dim3(64, 16), 256, 0, stream>>>(W2, W2T, 512, 512);
  transpose_kernel<<<dim3(64, 16), 256, 0, stream>>>(U2, U2T, 512, 512);

  auto mkL1 = [&](int t) {
    CellParams p;
    p.A0 = XP + (size_t)t * 131072; p.B0 = W1T; p.lda0 = 128; p.ldb0 = 128; p.nkt0 = 4;
    p.A1 = H1 + (size_t)(t & 1) * 524288; p.B1 = U1T; p.lda1 = 512; p.ldb1 = 512; p.nkt1 = 16;
    p.bias = b1; p.C = C1; p.H = H1 + (size_t)((t + 1) & 1) * 524288;
    return p;
  };
  auto mkL2 = [&](int t) {
    CellParams p;
    p.A0 = H1 + (size_t)((t + 1) & 1) * 524288; p.B0 = W2T; p.lda0 = 512; p.ldb0 = 512; p.nkt0 = 16;
    p.A1 = H2 + (size_t)(t & 1) * 524288; p.B1 = U2T; p.lda1 = 512; p.ldb1 = 512; p.nkt1 = 16;
    p.bias = b2; p.C = C2; p.H = H2 + (size_t)((t + 1) & 1) * 524288;
    return p;
  };

  cell_kernel<<<128, 512, 0, stream>>>(mkL1(0), mkL1(0));
  for (int k = 1; k < T_; ++k)
    cell_kernel<<<256, 512, 0, stream>>>(mkL2(k - 1), mkL1(k));  // layer2(k-1) || layer1(k)
  cell_kernel<<<128, 512, 0, stream>>>(mkL2(T_ - 1), mkL2(T_ - 1));

  // final h2 in buffer (T_&1)==0
  output_kernel<<<256, 256, 0, stream>>>(H2, Wout, bout, out);
}